// Round 12
// baseline (36.890 us; speedup 1.0000x reference)
//
#include <hip/hip_runtime.h>
#include <hip/hip_bf16.h>

// Problem constants
#define BB 64
#define CC 512
#define DD 256
// loss = mean_{b,c} [ log(sum_k exp(2*S_bck)) - 2*S_bcc ],  S = Vn . Tn^T (rows L2-normalized)

typedef __attribute__((ext_vector_type(8))) short bf16x8;  // 8 bf16 = 4 VGPRs
typedef __attribute__((ext_vector_type(4))) float f32x4;
typedef unsigned int u32;

#define SWZ(r) (((r) & 7) << 4)

__device__ inline short f2bf(float f) {
    union { __hip_bfloat16 h; short s; } cv;
    cv.h = __float2bfloat16(f);
    return cv.s;
}

// ---------------- Pass 1: L2-normalize T rows (fp32 in -> bf16 out), ~85% HBM ----------------
__global__ __launch_bounds__(256) void norm_rows(const float* __restrict__ in,
                                                 unsigned short* __restrict__ out) {
    const int row  = blockIdx.x * 4 + (threadIdx.x >> 6);
    const int lane = threadIdx.x & 63;
    const float4 x = reinterpret_cast<const float4*>(in)[(size_t)row * 64 + lane];
    float ss = x.x * x.x + x.y * x.y + x.z * x.z + x.w * x.w;
#pragma unroll
    for (int off = 32; off; off >>= 1) ss += __shfl_xor(ss, off);
    const float r = 1.0f / fmaxf(sqrtf(ss), 1e-12f);
    ushort4 o;
    o.x = (unsigned short)f2bf(x.x * r);
    o.y = (unsigned short)f2bf(x.y * r);
    o.z = (unsigned short)f2bf(x.z * r);
    o.w = (unsigned short)f2bf(x.w * r);
    reinterpret_cast<ushort4*>(out)[(size_t)row * 64 + lane] = o;
}

// ---------------- Pass 2: fused V-norm + GEMM + loss — LDS-READ-MINIMIZED WAVE SPLIT ----
// 256 blocks = 64 batches x 4 row-blocks of 128 V-rows; 512 threads (8 waves).
// Wave split: wr=wave>>2 owns a 64-row band (a[4][8]=128 VGPR); wc=wave&3 owns a 16-col
// quarter of each 64-col tile -> per tile per wave 8 ds_read : 32 MFMA (4:1), and each
// staged B row is read by only 2 waves (was 4) -> LDS-read volume halved vs R11.
// 8 tile-phases (64 T-rows, 32 KB), FOUR buffers, DMA depth 3 (counted s_waitcnt vmcnt(8),
// never drained mid-loop), ONE barrier per tile (stage(t+3) overwrites buf[(t-1)%4];
// barrier t proves t-1 consumed -> WAR-safe). A normalized in prologue, cached in regs.
__global__ __launch_bounds__(512, 1) void gemm_loss(const float* __restrict__ V,
                                                    const unsigned short* __restrict__ Tn,
                                                    float* __restrict__ partials) {
    extern __shared__ char lds[];  // 4 x 32KB tile buffers (prologue: A staging in [0,64K))
    float* vred = reinterpret_cast<float*>(lds + 131072);  // [128 rows][4 wc]
    float* dred = vred + 512;                              // [128 rows][4 wc]
    float* red2 = dred + 512;                              // [2]

    // XCD-aware remap: the 4 rb-blocks of one batch land on one XCD (Tn panel L2 reuse)
    const int i0    = blockIdx.x;  // 0..255
    const int inner = i0 & 63;
    const int b     = (inner & 7) * 8 + (inner >> 3);  // bijective over 0..63
    const int rb    = i0 >> 6;                         // 0..3

    const int tid  = threadIdx.x;  // 0..511
    const int lane = tid & 63;
    const int wave = tid >> 6;     // 0..7
    const int wr   = wave >> 2;    // 64-row band (0..1)
    const int wc   = wave & 3;     // 16-col quarter of each 64-col tile (0..3)
    const int g    = lane >> 4;    // k-group 0..3
    const int ln   = lane & 15;

    const float* gV = V + (size_t)b * (CC * DD) + (size_t)rb * 128 * DD;
    const char*  gT = reinterpret_cast<const char*>(Tn + (size_t)b * (CC * DD));  // 512 B rows

    // ---- A prologue: load 128 fp32 V rows, L2-normalize, write bf16 swizzled to lds ----
    {
        const int rrow  = tid >> 3;        // 8 threads/row, 64 rows/pass
        const int ecolB = (tid & 7) * 64;  // byte offset of this thread's 32 bf16 elems
#pragma unroll
        for (int p = 0; p < 2; ++p) {
            const int row = p * 64 + rrow;
            const float4* src =
                reinterpret_cast<const float4*>(gV + (size_t)row * DD) + (tid & 7) * 8;
            float4 x[8];
#pragma unroll
            for (int q = 0; q < 8; ++q) x[q] = src[q];
            float ss = 0.f;
#pragma unroll
            for (int q = 0; q < 8; ++q)
                ss += x[q].x * x[q].x + x[q].y * x[q].y + x[q].z * x[q].z + x[q].w * x[q].w;
            ss += __shfl_xor(ss, 1);
            ss += __shfl_xor(ss, 2);
            ss += __shfl_xor(ss, 4);  // 8 lanes own the row
            const float rinv = 1.0f / fmaxf(sqrtf(ss), 1e-12f);
            char* dstrow = lds + row * 512;
            const int sw = SWZ(row);
#pragma unroll
            for (int q2 = 0; q2 < 4; ++q2) {
                const float4 v0 = x[2 * q2], v1 = x[2 * q2 + 1];
                bf16x8 o;
                o[0] = f2bf(v0.x * rinv); o[1] = f2bf(v0.y * rinv);
                o[2] = f2bf(v0.z * rinv); o[3] = f2bf(v0.w * rinv);
                o[4] = f2bf(v1.x * rinv); o[5] = f2bf(v1.y * rinv);
                o[6] = f2bf(v1.z * rinv); o[7] = f2bf(v1.w * rinv);
                *reinterpret_cast<bf16x8*>(dstrow + ((ecolB + q2 * 16) ^ sw)) = o;
            }
        }
    }
    __syncthreads();

    // ---- cache this wave's A fragments: rows [wr*64, +64) -> a[4][8] = 128 VGPR ----
    bf16x8 a[4][8];
#pragma unroll
    for (int i = 0; i < 4; ++i) {
        const int row  = wr * 64 + i * 16 + ln;
        const char* rp = lds + row * 512;
        const int sw   = SWZ(row);
#pragma unroll
        for (int kk = 0; kk < 8; ++kk)
            a[i][kk] = *reinterpret_cast<const bf16x8*>(rp + ((kk * 64 + g * 16) ^ sw));
    }
    __syncthreads();  // implicit vmcnt(0): clean counter; lds free for tile buffers

    // ---- DMA stage: tile t = 64 Tn rows (32 KB) -> buf[t%4]; wave stages rows [wave*8,+8) ----
    auto stage = [&](int t) {
        const char* gtile = gT + (size_t)t * 32768;
        char* dst = lds + (t & 3) * 32768 + wave * 4096;
#pragma unroll
        for (int r2 = 0; r2 < 4; ++r2) {
            const int L   = r2 * 1024 + (lane << 4);
            const int lr  = L >> 9;  // 0..7 local row (within wave's 8)
            const int row = wave * 8 + lr;
            const int inrow = L & 511;
            __builtin_amdgcn_global_load_lds(
                (const u32*)(gtile + (size_t)row * 512 + (inrow ^ SWZ(row))),
                (u32*)(dst + r2 * 1024), 16, 0, 0);
        }
    };
    stage(0);
    stage(1);
    stage(2);  // 12 loads in flight per wave (depth 3)

    float rs[4][4];  // rowsum of exp(2S) over this wave's cols, per (i, r)
    float dg[4][4];  // diagonal 2*S term
#pragma unroll
    for (int i = 0; i < 4; ++i)
#pragma unroll
        for (int r = 0; r < 4; ++r) { rs[i][r] = 0.f; dg[i][r] = 0.f; }

    for (int t = 0; t < 8; ++t) {  // NOT unrolled (register pressure)
        // counted wait: my 4 tile-t loads landed (t+1,t+2's 8 stay in flight); then all waves'
        if (t < 6)       asm volatile("s_waitcnt vmcnt(8)" ::: "memory");
        else if (t == 6) asm volatile("s_waitcnt vmcnt(4)" ::: "memory");
        else             asm volatile("s_waitcnt vmcnt(0)" ::: "memory");
        __builtin_amdgcn_s_barrier();
        __builtin_amdgcn_sched_barrier(0);
        // stage t+3 into buf[(t+3)%4] = buf[(t-1)%4]; the barrier above proved every wave
        // finished consuming tile t-1 -> WAR-safe with ONE barrier per tile
        if (t < 5) stage(t + 3);

        // ---- consume tile t: 8 ds_read + 32 MFMA (wave's 16-col quarter; 4:1 ratio) ----
        const char* bufp = lds + (t & 3) * 32768;
        const int brow   = wc * 16 + ln;  // B row this lane reads (same for both wr-waves)
        const char* rp   = bufp + brow * 512;
        const int sw     = SWZ(brow);
        f32x4 acc[4];
#pragma unroll
        for (int i = 0; i < 4; ++i) acc[i] = (f32x4){0.f, 0.f, 0.f, 0.f};
        __builtin_amdgcn_s_setprio(1);
#pragma unroll
        for (int kk = 0; kk < 8; ++kk) {
            const bf16x8 bb = *reinterpret_cast<const bf16x8*>(rp + ((kk * 64 + g * 16) ^ sw));
            acc[0] = __builtin_amdgcn_mfma_f32_16x16x32_bf16(a[0][kk], bb, acc[0], 0, 0, 0);
            acc[1] = __builtin_amdgcn_mfma_f32_16x16x32_bf16(a[1][kk], bb, acc[1], 0, 0, 0);
            acc[2] = __builtin_amdgcn_mfma_f32_16x16x32_bf16(a[2][kk], bb, acc[2], 0, 0, 0);
            acc[3] = __builtin_amdgcn_mfma_f32_16x16x32_bf16(a[3][kk], bb, acc[3], 0, 0, 0);
        }
        __builtin_amdgcn_s_setprio(0);

        // ---- fused epilogue: exp(2*S) partial rowsum; diagonal gated to its 2 tiles ----
        const int gcol = t * 64 + wc * 16 + ln;
        if ((t >> 1) == rb) {
#pragma unroll
            for (int i = 0; i < 4; ++i) {
                const int grow = rb * 128 + wr * 64 + i * 16 + g * 4;  // + r
#pragma unroll
                for (int r = 0; r < 4; ++r) {
                    const float s2 = acc[i][r] * 2.0f;
                    rs[i][r] += __expf(s2);
                    if (gcol == grow + r) dg[i][r] += s2;
                }
            }
        } else {
#pragma unroll
            for (int i = 0; i < 4; ++i)
#pragma unroll
                for (int r = 0; r < 4; ++r) rs[i][r] += __expf(acc[i][r] * 2.0f);
        }
    }

    // ---- per-row completion: combine the four wc-quarters' exp-sums BEFORE log ----
#pragma unroll
    for (int i = 0; i < 4; ++i)
#pragma unroll
        for (int r = 0; r < 4; ++r) {
            float v = rs[i][r];
            float d = dg[i][r];
#pragma unroll
            for (int m = 1; m < 16; m <<= 1) {  // reduce the 16 column-lanes
                v += __shfl_xor(v, m);
                d += __shfl_xor(d, m);
            }
            if (ln == 0) {
                const int rl = wr * 64 + i * 16 + g * 4 + r;  // local row 0..127
                vred[rl * 4 + wc] = v;
                dred[rl * 4 + wc] = d;
            }
        }
    __syncthreads();

    if (tid < 128) {
        const float vv =
            vred[tid * 4] + vred[tid * 4 + 1] + vred[tid * 4 + 2] + vred[tid * 4 + 3];
        const float dd =
            dred[tid * 4] + dred[tid * 4 + 1] + dred[tid * 4 + 2] + dred[tid * 4 + 3];
        float lsum = logf(vv) - dd;
#pragma unroll
        for (int m = 1; m < 64; m <<= 1) lsum += __shfl_xor(lsum, m);
        if (lane == 0) red2[wave] = lsum;  // waves 0,1
    }
    __syncthreads();
    if (tid == 0) partials[i0] = red2[0] + red2[1];
}

// ---------------- Pass 3: final deterministic reduce (256 partials) ----------------
__global__ __launch_bounds__(256) void final_reduce(const float* __restrict__ partials,
                                                    float* __restrict__ out) {
    const int t = threadIdx.x;
    float v = partials[t];
#pragma unroll
    for (int m = 1; m < 64; m <<= 1) v += __shfl_xor(v, m);
    __shared__ float red[4];
    if ((t & 63) == 0) red[t >> 6] = v;
    __syncthreads();
    if (t == 0) out[0] = (red[0] + red[1] + red[2] + red[3]) * (1.0f / 32768.0f);
}

extern "C" void kernel_launch(void* const* d_in, const int* in_sizes, int n_in,
                              void* d_out, int out_size, void* d_ws, size_t ws_size,
                              hipStream_t stream) {
    const float* vis = (const float*)d_in[0];
    const float* txt = (const float*)d_in[1];

    unsigned short* Tn = (unsigned short*)d_ws;                             // 16.8 MB
    float* partials    = (float*)((char*)d_ws + (size_t)BB * CC * DD * 2);  // 256 floats
    float* out         = (float*)d_out;

    const int lds_bytes = 131072 + 512 * 4 + 512 * 4 + 16;
    hipFuncSetAttribute((const void*)gemm_loss, hipFuncAttributeMaxDynamicSharedMemorySize,
                        lds_bytes);

    norm_rows<<<8192, 256, 0, stream>>>(txt, Tn);
    gemm_loss<<<256, 512, lds_bytes, stream>>>(vis, Tn, partials);
    final_reduce<<<1, 256, 0, stream>>>(partials, out);
}